// Round 3
// baseline (817.100 us; speedup 1.0000x reference)
//
#include <hip/hip_runtime.h>

#define BATCH 2
#define NN 8192
#define DD 256
#define BK 64

typedef __attribute__((ext_vector_type(8))) short bf16x8;   // 8 bf16 = 4 VGPR
typedef __attribute__((ext_vector_type(4))) float f32x4;

__device__ __forceinline__ unsigned short f2bf(float f) {
    unsigned u = __builtin_bit_cast(unsigned, f);
    u += 0x7fffu + ((u >> 16) & 1u);          // RNE
    return (unsigned short)(u >> 16);
}

// ---- kernel 1: FUSED logmap0 scale + scaled transpose to bf16 ----
// layout xtf[b][kb][d][nn] (kb = n/64, nn = n%64).
// 4 threads per row: each holds 64 floats in regs, 2-lane-shfl row norm, then
// scale+convert from registers (x is read exactly once).
__global__ __launch_bounds__(256) void k_prep(const float* __restrict__ x,
                                              unsigned short* __restrict__ xtf) {
    __shared__ __align__(16) unsigned short T[DD][72];   // [d][r], stride 72 breaks conflicts
    int bid = blockIdx.x;                  // 0..255
    int b = bid >> 7, kb = bid & 127;
    int bn0 = b * NN + kb * 64;
    int t = threadIdx.x;
    int r = t >> 2, cc = t & 3;            // row-in-tile, 64-float chunk
    const float4* rp = (const float4*)(x + (size_t)(bn0 + r) * DD + cc * 64);
    float4 v[16];
    float s = 0.0f;
#pragma unroll
    for (int j = 0; j < 16; ++j) {
        v[j] = rp[j];
        s += v[j].x * v[j].x + v[j].y * v[j].y + v[j].z * v[j].z + v[j].w * v[j].w;
    }
    s += __shfl_xor(s, 1, 64);             // 4 lanes share a row (lane bits 0-1 = cc)
    s += __shfl_xor(s, 2, 64);
    float n = fmaxf(sqrtf(s), 1e-15f);
    float z = fminf(n, 1.0f - 1e-7f);
    float at = 0.5f * logf((1.0f + z) / (1.0f - z));   // artanh
    float sc = at / n;
#pragma unroll
    for (int j = 0; j < 16; ++j) {
        int d = cc * 64 + j * 4;
        T[d + 0][r] = f2bf(v[j].x * sc);
        T[d + 1][r] = f2bf(v[j].y * sc);
        T[d + 2][r] = f2bf(v[j].z * sc);
        T[d + 3][r] = f2bf(v[j].w * sc);
    }
    __syncthreads();
    unsigned short* outp = xtf + (size_t)(b * 128 + kb) * DD * 64;
    int dd = t >> 3, ccc = t & 7;
#pragma unroll
    for (int p = 0; p < 8; ++p) {
        int d = dd + 32 * p;
        bf16x8 val = *(const bf16x8*)&T[d][ccc * 8];
        *(bf16x8*)(outp + (size_t)d * 64 + ccc * 8) = val;   // fully coalesced
    }
}

// ---- kernel 2: GEMM (adj fp32 -> bf16 MFMA) + fused expmap0/project epilogue ----
// 512 blocks x 256 thr (4 waves) = 2 blocks/CU: independent barriers overlap.
// Tile 32 rows x 256 cols (full D -> row norm block-local).
// Single __syncthreads per K-step via LDS double-buffer; depth-2 reg prefetch A & B.
__global__ __launch_bounds__(256, 2) void k_gemm(const float* __restrict__ adj,
                                                 const unsigned short* __restrict__ xtf,
                                                 float* __restrict__ out) {
    __shared__ __align__(16) unsigned short A_lds[2][32][72];  // double-buffered A tile
    __shared__ float red[4][32];
    __shared__ float rowscale[32];

    int bid = blockIdx.x;                  // 0..511
    // XCD swizzle: XCDs 0-3 -> batch 0, XCDs 4-7 -> batch 1 (xtf[b] stays in XCD L2)
    int xcd = bid & 7;
    int b = xcd >> 2;
    int mtile = ((bid >> 3) << 2) | (xcd & 3);   // bijective over 0..255 per batch
    int m0 = mtile * 32;

    int t = threadIdx.x;
    int w = t >> 6, lane = t & 63, c = lane & 15, q = lane >> 4;

    // A staging: thread loads float4 at rows {t>>4, 16+(t>>4)}, col4 = t&15 (coalesced)
    int ar = t >> 4;
    int ac4 = t & 15;
    const float* abase = adj + (size_t)b * NN * NN + (size_t)(m0 + ar) * NN + ac4 * 4;

    // B fragments straight from global (L2-resident): lane holds xt^T[col][k..k+8)
    const unsigned short* xbase = xtf + (size_t)b * 128 * DD * 64
                                + (size_t)(w * 64 + c) * 64 + q * 8;

    f32x4 acc[2][4];
#pragma unroll
    for (int i = 0; i < 2; ++i)
#pragma unroll
        for (int j = 0; j < 4; ++j)
#pragma unroll
            for (int rg = 0; rg < 4; ++rg) acc[i][j][rg] = 0.0f;

    float4 av[2][2];       // [parity][row-half] — all indices compile-time after unroll
    bf16x8 bfr[2][4][2];   // [parity][nt][kk]

    // prologue: kb = 0 (parity 0) and kb = 1 (parity 1)
#pragma unroll
    for (int p = 0; p < 2; ++p) {
        const float* ab = abase + (size_t)p * BK;
#pragma unroll
        for (int i = 0; i < 2; ++i)
            av[p][i] = *(const float4*)(ab + (size_t)(i * 16) * NN);
        const unsigned short* xb = xbase + (size_t)p * DD * 64;
#pragma unroll
        for (int nt = 0; nt < 4; ++nt)
#pragma unroll
            for (int kk = 0; kk < 2; ++kk)
                bfr[p][nt][kk] = *(const bf16x8*)(xb + nt * 16 * 64 + kk * 32);
    }

    for (int kb2 = 0; kb2 < 128; kb2 += 2) {
#pragma unroll
        for (int p = 0; p < 2; ++p) {
            int kb = kb2 + p;
            // convert current A regs -> LDS buffer p
#pragma unroll
            for (int i = 0; i < 2; ++i) {
                ushort4 pk;
                pk.x = f2bf(av[p][i].x); pk.y = f2bf(av[p][i].y);
                pk.z = f2bf(av[p][i].z); pk.w = f2bf(av[p][i].w);
                *(ushort4*)&A_lds[p][ar + i * 16][ac4 * 4] = pk;
            }
            // depth-2 A prefetch (same parity, tile kb+2) — flies during barrier+MFMA
            if (kb + 2 < 128) {
                const float* ab = abase + (size_t)(kb + 2) * BK;
#pragma unroll
                for (int i = 0; i < 2; ++i)
                    av[p][i] = *(const float4*)(ab + (size_t)(i * 16) * NN);
            }
            __syncthreads();   // single barrier per K-step: LDS[p] write->read
            // (safe: LDS[p] reuse distance is 2 steps; reads of step kb-2 completed
            //  before their MFMAs, which precede the kb-1 barrier all waves passed)
#pragma unroll
            for (int kk = 0; kk < 2; ++kk) {
                bf16x8 af[2];
#pragma unroll
                for (int mt = 0; mt < 2; ++mt)
                    af[mt] = *(const bf16x8*)&A_lds[p][mt * 16 + c][kk * 32 + q * 8];
#pragma unroll
                for (int mt = 0; mt < 2; ++mt)
#pragma unroll
                    for (int nt = 0; nt < 4; ++nt)
                        acc[mt][nt] = __builtin_amdgcn_mfma_f32_16x16x32_bf16(
                            af[mt], bfr[p][nt][kk], acc[mt][nt], 0, 0, 0);
            }
            // depth-2 B prefetch (tile kb+2), issued after MFMA consumed bfr[p]
            if (kb + 2 < 128) {
                const unsigned short* xb = xbase + (size_t)(kb + 2) * DD * 64;
#pragma unroll
                for (int nt = 0; nt < 4; ++nt)
#pragma unroll
                    for (int kk = 0; kk < 2; ++kk)
                        bfr[p][nt][kk] = *(const bf16x8*)(xb + nt * 16 * 64 + kk * 32);
            }
        }
    }

    // ---- epilogue: row norms over full D, then out = min(tanh(n), 1-4e-3)/n * u ----
    // C/D layout: col = lane&15 (=c), row-in-16 = q*4 + reg
    float sred[2][4];
#pragma unroll
    for (int mt = 0; mt < 2; ++mt)
#pragma unroll
        for (int rg = 0; rg < 4; ++rg) {
            float v = acc[mt][0][rg] * acc[mt][0][rg] + acc[mt][1][rg] * acc[mt][1][rg]
                    + acc[mt][2][rg] * acc[mt][2][rg] + acc[mt][3][rg] * acc[mt][3][rg];
            v += __shfl_xor(v, 1, 64);
            v += __shfl_xor(v, 2, 64);
            v += __shfl_xor(v, 4, 64);
            v += __shfl_xor(v, 8, 64);    // sum over this wave's 64 cols
            sred[mt][rg] = v;
        }
#pragma unroll
    for (int mt = 0; mt < 2; ++mt)
#pragma unroll
        for (int rg = 0; rg < 4; ++rg)
            if (c == mt * 4 + rg)
                red[w][mt * 16 + q * 4 + rg] = sred[mt][rg];
    __syncthreads();
    if (t < 32) {
        float tot = red[0][t] + red[1][t] + red[2][t] + red[3][t];
        float n = fmaxf(sqrtf(tot), 1e-15f);
        float th = tanhf(n);
        rowscale[t] = fminf(th, 1.0f - 4e-3f) / n;   // expmap0 + project fused
    }
    __syncthreads();

    float* obase = out + ((size_t)b * NN + m0) * DD + w * 64 + c;
#pragma unroll
    for (int mt = 0; mt < 2; ++mt)
#pragma unroll
        for (int rg = 0; rg < 4; ++rg) {
            float rs = rowscale[mt * 16 + q * 4 + rg];
            float* orow = obase + (size_t)(mt * 16 + q * 4 + rg) * DD;
#pragma unroll
            for (int nt = 0; nt < 4; ++nt)
                orow[nt * 16] = acc[mt][nt][rg] * rs;
        }
}

extern "C" void kernel_launch(void* const* d_in, const int* in_sizes, int n_in,
                              void* d_out, int out_size, void* d_ws, size_t ws_size,
                              hipStream_t stream) {
    const float* x   = (const float*)d_in[0];   // [2, 8192, 256] fp32
    const float* adj = (const float*)d_in[1];   // [2, 8192, 8192] fp32
    float* out = (float*)d_out;                 // [2, 8192, 256] fp32

    unsigned short* xtf = (unsigned short*)d_ws;   // 8 MiB bf16 xt^T tiles

    k_prep<<<BATCH * 128, 256, 0, stream>>>(x, xtf);
    k_gemm<<<512, 256, 0, stream>>>(adj, xtf, out);
}

// Round 4
// 767.953 us; speedup vs baseline: 1.0640x; 1.0640x over previous
//
#include <hip/hip_runtime.h>

#define BATCH 2
#define NN 8192
#define DD 256
#define BK 64

typedef __attribute__((ext_vector_type(8))) short bf16x8;   // 8 bf16 = 4 VGPR
typedef __attribute__((ext_vector_type(4))) float f32x4;

__device__ __forceinline__ unsigned short f2bf(float f) {
    unsigned u = __builtin_bit_cast(unsigned, f);
    u += 0x7fffu + ((u >> 16) & 1u);          // RNE
    return (unsigned short)(u >> 16);
}

// ---- kernel 1: FUSED logmap0 scale + scaled transpose to bf16 ----
// layout xtf[b][kb][d][nn] (kb = n/64, nn = n%64). x is read exactly once.
__global__ __launch_bounds__(256) void k_prep(const float* __restrict__ x,
                                              unsigned short* __restrict__ xtf) {
    __shared__ __align__(16) unsigned short T[DD][72];   // [d][r], stride 72 breaks conflicts
    int bid = blockIdx.x;                  // 0..255
    int b = bid >> 7, kb = bid & 127;
    int bn0 = b * NN + kb * 64;
    int t = threadIdx.x;
    int r = t >> 2, cc = t & 3;            // row-in-tile, 64-float chunk
    const float4* rp = (const float4*)(x + (size_t)(bn0 + r) * DD + cc * 64);
    float4 v[16];
    float s = 0.0f;
#pragma unroll
    for (int j = 0; j < 16; ++j) {
        v[j] = rp[j];
        s += v[j].x * v[j].x + v[j].y * v[j].y + v[j].z * v[j].z + v[j].w * v[j].w;
    }
    s += __shfl_xor(s, 1, 64);             // 4 lanes share a row (lane bits 0-1 = cc)
    s += __shfl_xor(s, 2, 64);
    float n = fmaxf(sqrtf(s), 1e-15f);
    float z = fminf(n, 1.0f - 1e-7f);
    float at = 0.5f * logf((1.0f + z) / (1.0f - z));   // artanh
    float sc = at / n;
#pragma unroll
    for (int j = 0; j < 16; ++j) {
        int d = cc * 64 + j * 4;
        T[d + 0][r] = f2bf(v[j].x * sc);
        T[d + 1][r] = f2bf(v[j].y * sc);
        T[d + 2][r] = f2bf(v[j].z * sc);
        T[d + 3][r] = f2bf(v[j].w * sc);
    }
    __syncthreads();
    unsigned short* outp = xtf + (size_t)(b * 128 + kb) * DD * 64;
    int dd = t >> 3, ccc = t & 7;
#pragma unroll
    for (int p = 0; p < 8; ++p) {
        int d = dd + 32 * p;
        bf16x8 val = *(const bf16x8*)&T[d][ccc * 8];
        *(bf16x8*)(outp + (size_t)d * 64 + ccc * 8) = val;   // fully coalesced
    }
}

// ---- kernel 2: GEMM (adj fp32 -> bf16 MFMA) + fused expmap0/project epilogue ----
// Round-0 geometry: 256 blocks x 256 thr, 64x256 tile (1 block/CU, minimal L2 B traffic).
// NEW: double-buffered A tile -> ONE barrier per K-step, and the barrier is a raw
// s_barrier with lgkmcnt(0) only — NO vmcnt drain. A/B prefetch loads stay
// compiler-tracked register loads, so hipcc emits counted vmcnt(N) at first use;
// depth-2 prefetch (~16-24 KB/wave in flight) covers ~900cy HBM latency.
__global__ __launch_bounds__(256, 1) void k_gemm(const float* __restrict__ adj,
                                                 const unsigned short* __restrict__ xtf,
                                                 float* __restrict__ out) {
    __shared__ __align__(16) unsigned short A_lds[2][64][72];  // double-buffered, stride 72
    __shared__ float red[4][64];
    __shared__ float rowscale[64];

    int bid = blockIdx.x;                  // 0..255
    // XCD swizzle: XCDs 0-3 -> batch 0, XCDs 4-7 -> batch 1 (xtf[b] stays in XCD L2)
    int xcd = bid & 7;
    int b = xcd >> 2;
    int mtile = ((bid >> 3) << 2) | (xcd & 3);   // bijective over 0..127
    int m0 = mtile * 64;

    int t = threadIdx.x;
    int w = t >> 6, lane = t & 63, c = lane & 15, q = lane >> 4;

    // A staging: thread loads float4 at (row = i*16 + t>>4, col4 = t&15) -> coalesced
    int ar = t >> 4;
    int ac4 = t & 15;
    const float* abase = adj + (size_t)b * NN * NN + (size_t)(m0 + ar) * NN + ac4 * 4;

    // B fragments straight from global (L2-resident): lane holds xt^T[col][k..k+8)
    const unsigned short* xbase = xtf + (size_t)b * 128 * DD * 64
                                + (size_t)(w * 64 + c) * 64 + q * 8;

    f32x4 acc[4][4];
#pragma unroll
    for (int i = 0; i < 4; ++i)
#pragma unroll
        for (int j = 0; j < 4; ++j)
#pragma unroll
            for (int rg = 0; rg < 4; ++rg) acc[i][j][rg] = 0.0f;

    float4 av[2][4];       // [parity][row-quarter] — all indices static after unroll
    bf16x8 bfr[2][4][2];   // [parity][nt][kk]

    // prologue: tiles kb = 0 (parity 0) and kb = 1 (parity 1)
#pragma unroll
    for (int p = 0; p < 2; ++p) {
        const float* ab = abase + (size_t)p * BK;
#pragma unroll
        for (int i = 0; i < 4; ++i)
            av[p][i] = *(const float4*)(ab + (size_t)(i * 16) * NN);
        const unsigned short* xb = xbase + (size_t)p * DD * 64;
#pragma unroll
        for (int nt = 0; nt < 4; ++nt)
#pragma unroll
            for (int kk = 0; kk < 2; ++kk)
                bfr[p][nt][kk] = *(const bf16x8*)(xb + nt * 16 * 64 + kk * 32);
    }

    for (int kb2 = 0; kb2 < 128; kb2 += 2) {
#pragma unroll
        for (int p = 0; p < 2; ++p) {
            int kb = kb2 + p;
            // W(kb): convert A regs -> LDS buffer p (compiler waits counted vmcnt here)
#pragma unroll
            for (int i = 0; i < 4; ++i) {
                ushort4 pk;
                pk.x = f2bf(av[p][i].x); pk.y = f2bf(av[p][i].y);
                pk.z = f2bf(av[p][i].z); pk.w = f2bf(av[p][i].w);
                *(ushort4*)&A_lds[p][ar + i * 16][ac4 * 4] = pk;
            }
            // S(kb+2): issue next-next A tile into the just-freed parity regs
            if (kb + 2 < 128) {
                const float* ab = abase + (size_t)(kb + 2) * BK;
#pragma unroll
                for (int i = 0; i < 4; ++i)
                    av[p][i] = *(const float4*)(ab + (size_t)(i * 16) * NN);
            }
            // barrier WITHOUT vmcnt drain: own ds_writes done, then raw s_barrier.
            // (LDS[p] reuse distance is 2 steps; the intervening barrier orders
            //  all waves' reads of step kb-2 before writes of step kb.)
            asm volatile("s_waitcnt lgkmcnt(0)" ::: "memory");
            __builtin_amdgcn_s_barrier();
            __builtin_amdgcn_sched_barrier(0);
            // C(kb): fragments + MFMA (B regs loaded 2 steps ago — latency covered)
#pragma unroll
            for (int kk = 0; kk < 2; ++kk) {
                bf16x8 af[4];
#pragma unroll
                for (int mt = 0; mt < 4; ++mt)
                    af[mt] = *(const bf16x8*)&A_lds[p][mt * 16 + c][kk * 32 + q * 8];
#pragma unroll
                for (int mt = 0; mt < 4; ++mt)
#pragma unroll
                    for (int nt = 0; nt < 4; ++nt)
                        acc[mt][nt] = __builtin_amdgcn_mfma_f32_16x16x32_bf16(
                            af[mt], bfr[p][nt][kk], acc[mt][nt], 0, 0, 0);
            }
            // L(kb+2): issue next-next B tile (L2-resident) into freed parity regs
            if (kb + 2 < 128) {
                const unsigned short* xb = xbase + (size_t)(kb + 2) * DD * 64;
#pragma unroll
                for (int nt = 0; nt < 4; ++nt)
#pragma unroll
                    for (int kk = 0; kk < 2; ++kk)
                        bfr[p][nt][kk] = *(const bf16x8*)(xb + nt * 16 * 64 + kk * 32);
            }
        }
    }

    // ---- epilogue: row norms over full D, then out = min(tanh(n), 1-4e-3)/n * u ----
    // C/D layout: col = lane&15 (=c), row-in-16 = q*4 + reg
    float sred[4][4];
#pragma unroll
    for (int mt = 0; mt < 4; ++mt)
#pragma unroll
        for (int rg = 0; rg < 4; ++rg) {
            float v = acc[mt][0][rg] * acc[mt][0][rg] + acc[mt][1][rg] * acc[mt][1][rg]
                    + acc[mt][2][rg] * acc[mt][2][rg] + acc[mt][3][rg] * acc[mt][3][rg];
            v += __shfl_xor(v, 1, 64);
            v += __shfl_xor(v, 2, 64);
            v += __shfl_xor(v, 4, 64);
            v += __shfl_xor(v, 8, 64);    // sum over the wave's 64 cols
            sred[mt][rg] = v;
        }
#pragma unroll
    for (int mt = 0; mt < 4; ++mt)
#pragma unroll
        for (int rg = 0; rg < 4; ++rg)
            if (c == mt * 4 + rg)
                red[w][mt * 16 + q * 4 + rg] = sred[mt][rg];
    __syncthreads();
    if (t < 64) {
        float tot = red[0][t] + red[1][t] + red[2][t] + red[3][t];
        float n = fmaxf(sqrtf(tot), 1e-15f);
        float th = tanhf(n);
        rowscale[t] = fminf(th, 1.0f - 4e-3f) / n;   // expmap0 + project fused
    }
    __syncthreads();

    float* obase = out + ((size_t)b * NN + m0) * DD + w * 64 + c;
#pragma unroll
    for (int mt = 0; mt < 4; ++mt)
#pragma unroll
        for (int rg = 0; rg < 4; ++rg) {
            float rs = rowscale[mt * 16 + q * 4 + rg];
            float* orow = obase + (size_t)(mt * 16 + q * 4 + rg) * DD;
#pragma unroll
            for (int nt = 0; nt < 4; ++nt)
                orow[nt * 16] = acc[mt][nt][rg] * rs;
        }
}

extern "C" void kernel_launch(void* const* d_in, const int* in_sizes, int n_in,
                              void* d_out, int out_size, void* d_ws, size_t ws_size,
                              hipStream_t stream) {
    const float* x   = (const float*)d_in[0];   // [2, 8192, 256] fp32
    const float* adj = (const float*)d_in[1];   // [2, 8192, 8192] fp32
    float* out = (float*)d_out;                 // [2, 8192, 256] fp32

    unsigned short* xtf = (unsigned short*)d_ws;   // 8 MiB bf16 xt^T tiles

    k_prep<<<BATCH * 128, 256, 0, stream>>>(x, xtf);
    k_gemm<<<256, 256, 0, stream>>>(adj, xtf, out);
}